// Round 1
// baseline (83.557 us; speedup 1.0000x reference)
//
#include <hip/hip_runtime.h>

#define N_ROWS 8192
#define N_DIM 256
#define N_CLS 10
#define K2_BLOCKS 256
#define ROWS_PER_BLOCK (N_ROWS / K2_BLOCKS)   // 32

// ws layout (bytes):
//   [0]    double termA
//   [64]   int counts[10]
//   [128]  float S[10][256]   (per-class vector sums over ALL rows)

// K1: class counts + zero-init scratch (ws is poisoned 0xAA each call).
__global__ __launch_bounds__(256)
void k1_counts_init(const int* __restrict__ label,
                    int* __restrict__ counts,
                    float* __restrict__ S,
                    double* __restrict__ termA) {
    __shared__ int c_loc[N_CLS];
    const int t = threadIdx.x;
    if (t < N_CLS) c_loc[t] = 0;
    __syncthreads();
    for (int r = t; r < N_ROWS; r += 256)
        atomicAdd(&c_loc[label[r]], 1);
    for (int i = t; i < N_CLS * N_DIM; i += 256)
        S[i] = 0.0f;
    if (t == 0) *termA = 0.0;
    __syncthreads();
    if (t < N_CLS) counts[t] = c_loc[t];
}

// K2: one pass over out[8192][256].
// thread t = dim index. Per row: accumulate v into per-class register sums
// (branchless select) and W_r * v^2 into a double accumulator.
__global__ __launch_bounds__(256)
void k2_main(const float* __restrict__ out,
             const int* __restrict__ label,
             const int* __restrict__ counts,
             float* __restrict__ S,
             double* __restrict__ termA) {
    __shared__ float sh_a[N_CLS];   // 2*n_C[c] - (N-1)  (applies when r <= N-2)
    __shared__ float sh_b[N_CLS];   // 2*n_R[c] - (N-1)  (applies when r >= 1)
    __shared__ int   sh_lbl[ROWS_PER_BLOCK];

    const int t = threadIdx.x;
    if (t < N_CLS) {
        const int l0 = label[0];
        const int lN = label[N_ROWS - 1];
        const int nC = counts[t] - (t == l0 ? 1 : 0);  // |{j in C : l_j = c}|
        const int nR = counts[t] - (t == lN ? 1 : 0);  // |{i in R : l_i = c}|
        sh_a[t] = (float)(2 * nC - (N_ROWS - 1));
        sh_b[t] = (float)(2 * nR - (N_ROWS - 1));
    }
    const int r0 = blockIdx.x * ROWS_PER_BLOCK;
    if (t < ROWS_PER_BLOCK) sh_lbl[t] = label[r0 + t];
    __syncthreads();

    float accS[N_CLS];
#pragma unroll
    for (int c = 0; c < N_CLS; ++c) accS[c] = 0.0f;
    double accW = 0.0;

    for (int rr = 0; rr < ROWS_PER_BLOCK; ++rr) {
        const int r = r0 + rr;
        const int l = sh_lbl[rr];
        const float v = out[r * N_DIM + t];
        float W = 0.0f;
        if (r < N_ROWS - 1) W += sh_a[l];
        if (r >= 1)         W += sh_b[l];
        accW += (double)W * (double)(v * v);
#pragma unroll
        for (int c = 0; c < N_CLS; ++c)
            accS[c] += (l == c) ? v : 0.0f;
    }

#pragma unroll
    for (int c = 0; c < N_CLS; ++c)
        atomicAdd(&S[c * N_DIM + t], accS[c]);

    // block-reduce accW (double), one global atomic per block
    __shared__ double red[256];
    red[t] = accW;
    __syncthreads();
    for (int s = 128; s > 0; s >>= 1) {
        if (t < s) red[t] += red[t + s];
        __syncthreads();
    }
    if (t == 0) atomicAdd(termA, red[0]);
}

// K3: term B from per-class sums with rank-1 edge corrections, final scale.
__global__ __launch_bounds__(256)
void k3_final(const float* __restrict__ out,
              const int* __restrict__ label,
              const float* __restrict__ S,
              const double* __restrict__ termA,
              float* __restrict__ result) {
    const int t = threadIdx.x;   // dim
    const int l0 = label[0];
    const int lN = label[N_ROWS - 1];
    const float x0 = out[t];                           // row 0
    const float xl = out[(N_ROWS - 1) * N_DIM + t];    // row N-1

    double Td = 0.0, dotRC = 0.0;
#pragma unroll
    for (int c = 0; c < N_CLS; ++c) {
        const double s = (double)S[c * N_DIM + t];
        Td += s;
        const double sR = s - (c == lN ? (double)xl : 0.0);
        const double sC = s - (c == l0 ? (double)x0 : 0.0);
        dotRC += sR * sC;
    }
    const double TR = Td - (double)xl;
    const double TC = Td - (double)x0;
    double val = -2.0 * (2.0 * dotRC - TR * TC);

    __shared__ double red[256];
    red[t] = val;
    __syncthreads();
    for (int s = 128; s > 0; s >>= 1) {
        if (t < s) red[t] += red[t + s];
        __syncthreads();
    }
    if (t == 0) {
        const double total = *termA + red[0];
        const double PAR = 1.0 * 0.5 / 8192.0;
        *result = (float)(PAR * total);
    }
}

extern "C" void kernel_launch(void* const* d_in, const int* in_sizes, int n_in,
                              void* d_out, int out_size, void* d_ws, size_t ws_size,
                              hipStream_t stream) {
    const float* out   = (const float*)d_in[0];
    const int*   label = (const int*)d_in[1];

    char*   ws     = (char*)d_ws;
    double* termA  = (double*)ws;
    int*    counts = (int*)(ws + 64);
    float*  S      = (float*)(ws + 128);

    k1_counts_init<<<1, 256, 0, stream>>>(label, counts, S, termA);
    k2_main<<<K2_BLOCKS, 256, 0, stream>>>(out, label, counts, S, termA);
    k3_final<<<1, 256, 0, stream>>>(out, label, S, termA, (float*)d_out);
}